// Round 1
// baseline (224.435 us; speedup 1.0000x reference)
//
#include <hip/hip_runtime.h>
#include <stdint.h>

typedef unsigned short u16;
typedef __attribute__((ext_vector_type(8))) short short8;   // 8 x bf16 (4 VGPRs)
typedef __attribute__((ext_vector_type(4))) float f32x4;    // 4 x fp32 acc

__device__ __forceinline__ u16 f2bf(float f) {
    union { float f; uint32_t u; } v; v.f = f;
    return (u16)((v.u + (0x7FFFu + ((v.u >> 16) & 1u))) >> 16);   // RNE
}

// ---------------- P1: W2[o][j] = sum_i U[o][i] * S[i][j]  (256x64, bf16 out) ----
__global__ void k_us(const float* __restrict__ U, const float* __restrict__ S,
                     u16* __restrict__ W2) {
    int t = blockIdx.x * 256 + threadIdx.x;        // 16384 threads
    int o = t >> 6, j = t & 63;
    float acc = 0.f;
#pragma unroll 8
    for (int i = 0; i < 64; ++i) acc += U[o * 64 + i] * S[i * 64 + j];
    W2[t] = f2bf(acc);
}

// ---------------- P2: Vt[r][tap*256 + c] = V[c*9 + tap][r]  (bf16) --------------
__global__ void k_vperm(const float* __restrict__ V, u16* __restrict__ Vt) {
    int t = blockIdx.x * 256 + threadIdx.x;        // 147456 threads
    int c = t & 255;
    int tap = (t >> 8) % 9;
    int r = t / 2304;
    Vt[t] = f2bf(V[(c * 9 + tap) * 64 + r]);
}

// ---------------- P3: xb[b][hp][wp][c] = pad(x) channels-last bf16 --------------
// xb: [16][58][58][256]; xb[hp][wp] = x[hp-1][wp-1] (zero outside)
__global__ void k_pad(const float* __restrict__ x, u16* __restrict__ xb) {
    int bi = blockIdx.x;                            // 16*58 = 928
    int b = bi / 58, hp = bi % 58;
    int c = threadIdx.x;                            // 256
    int h = hp - 1;
    bool hv = (h >= 0) && (h < 56);
    const float* xrow = x + (((b * 256 + c) * 56 + (hv ? h : 0)) * 56);
    u16* orow = xb + ((size_t)(b * 58 + hp) * 58) * 256 + c;
    for (int wp = 0; wp < 58; ++wp) {
        int w = wp - 1;
        float v = (hv && w >= 0 && w < 56) ? xrow[w] : 0.f;
        orow[wp * 256] = f2bf(v);
    }
}

// ---------------- Stage A: y1[b][l][r] = conv(xb, Vt)  -------------------------
// block = one (b, h) output row: BM=64 (r), BN=64 (w; 56 valid), K=2304
// LDS tile: [di 0..2][wp 0..65][c-slot 40 (32 used)] bf16, all 9 taps reuse it.
#define WPS 40                                      // padded c-stride (bank spread)
__global__ __launch_bounds__(256) void k_convA(const u16* __restrict__ xb,
                                               const u16* __restrict__ Vt,
                                               u16* __restrict__ y1) {
    __shared__ u16 lds_x[3 * 66 * WPS];             // 15840 B
    int bi = blockIdx.x;                            // 896 = 16*56
    int b = bi & 15, h = bi >> 4;
    int tid = threadIdx.x;
    int wv = tid >> 6;                              // wave id: m-tile (16 r's)
    int ln = tid & 63;
    int lane15 = ln & 15, quad = ln >> 4;

    f32x4 acc[4];
#pragma unroll
    for (int nt = 0; nt < 4; ++nt) acc[nt] = (f32x4){0.f, 0.f, 0.f, 0.f};

    for (int chunk = 0; chunk < 8; ++chunk) {
        int c0 = chunk * 32;
        __syncthreads();
        // stage 3 rows x 66 wp x 32 c as 16B chunks: 3*66*4 = 792 chunks
        for (int idx = tid; idx < 792; idx += 256) {
            int q  = idx & 3;
            int rm = idx >> 2;
            int wp = rm % 66;
            int di = rm / 66;
            uint4 val = make_uint4(0u, 0u, 0u, 0u);
            if (wp < 58) {
                const uint4* src = (const uint4*)(xb +
                    (((size_t)(b * 58 + (h + di)) * 58 + wp) << 8) + c0 + q * 8);
                val = *src;
            }
            *(uint4*)&lds_x[(di * 66 + wp) * WPS + q * 8] = val;
        }
        __syncthreads();
#pragma unroll
        for (int tap = 0; tap < 9; ++tap) {
            const int di = tap / 3, dj = tap % 3;
            // A fragment straight from global (Vt row-major, contiguous k) — L2-hot
            short8 a = *(const short8*)(Vt + (size_t)(wv * 16 + lane15) * 2304
                                        + tap * 256 + c0 + quad * 8);
#pragma unroll
            for (int nt = 0; nt < 4; ++nt) {
                int n = nt * 16 + lane15;
                short8 bv = *(const short8*)&lds_x[(di * 66 + n + dj) * WPS + quad * 8];
                acc[nt] = __builtin_amdgcn_mfma_f32_16x16x32_bf16(a, bv, acc[nt], 0, 0, 0);
            }
        }
    }
    // epilogue: C layout col=lane&15 (n), row=quad*4+reg (m) -> y1[b][l][r] bf16
#pragma unroll
    for (int nt = 0; nt < 4; ++nt) {
        int n = nt * 16 + lane15;
        if (n < 56) {
            int l = h * 56 + n;
            int r = wv * 16 + quad * 4;
            uint2 pv;
            pv.x = (uint32_t)f2bf(acc[nt][0]) | ((uint32_t)f2bf(acc[nt][1]) << 16);
            pv.y = (uint32_t)f2bf(acc[nt][2]) | ((uint32_t)f2bf(acc[nt][3]) << 16);
            *(uint2*)(y1 + ((size_t)(b * 3136 + l) << 6) + r) = pv;
        }
    }
}

// ---------------- Stage B: out[b][o][l] = W2[o][:] . y1[b][l][:] + bias[o] -----
// block: BM=256 (wave wv -> o in [wv*64, wv*64+64)), BN=64 (l), K=64
__global__ __launch_bounds__(256) void k_gemmB(const u16* __restrict__ y1,
                                               const u16* __restrict__ W2,
                                               const float* __restrict__ bias,
                                               float* __restrict__ out) {
    __shared__ u16 lds_y[64 * 72];                  // 9216 B, 72 stride = bank spread
    int bi = blockIdx.x;                            // 784 = 16*49
    int b = bi % 16, lt = bi / 16;
    int l0 = lt * 64;
    int tid = threadIdx.x;
    int wv = tid >> 6, ln = tid & 63;
    int lane15 = ln & 15, quad = ln >> 4;

    // stage y1 tile [64 n][64 r]: 64*8 = 512 16B chunks
    for (int idx = tid; idx < 512; idx += 256) {
        int q = idx & 7, n = idx >> 3;
        uint4 v = *(const uint4*)(y1 + (((size_t)(b * 3136 + l0 + n)) << 6) + q * 8);
        *(uint4*)&lds_y[n * 72 + q * 8] = v;
    }
    __syncthreads();

    f32x4 acc[4][4];
#pragma unroll
    for (int mt = 0; mt < 4; ++mt)
#pragma unroll
        for (int nt = 0; nt < 4; ++nt) acc[mt][nt] = (f32x4){0.f, 0.f, 0.f, 0.f};

    int o0 = wv * 64;
#pragma unroll
    for (int ks = 0; ks < 64; ks += 32) {
        short8 a[4];
#pragma unroll
        for (int mt = 0; mt < 4; ++mt)
            a[mt] = *(const short8*)(W2 + (size_t)(o0 + mt * 16 + lane15) * 64
                                     + ks + quad * 8);
#pragma unroll
        for (int nt = 0; nt < 4; ++nt) {
            short8 bv = *(const short8*)&lds_y[(nt * 16 + lane15) * 72 + ks + quad * 8];
#pragma unroll
            for (int mt = 0; mt < 4; ++mt)
                acc[mt][nt] = __builtin_amdgcn_mfma_f32_16x16x32_bf16(a[mt], bv, acc[mt][nt], 0, 0, 0);
        }
    }

#pragma unroll
    for (int mt = 0; mt < 4; ++mt) {
        int ob = o0 + mt * 16 + quad * 4;
#pragma unroll
        for (int reg = 0; reg < 4; ++reg) {
            int o = ob + reg;
            float bvl = bias[o];
            float* orow = out + ((size_t)(b * 256 + o)) * 3136 + l0 + lane15;
#pragma unroll
            for (int nt = 0; nt < 4; ++nt)
                orow[nt * 16] = acc[mt][nt][reg] + bvl;
        }
    }
}

extern "C" void kernel_launch(void* const* d_in, const int* in_sizes, int n_in,
                              void* d_out, int out_size, void* d_ws, size_t ws_size,
                              hipStream_t stream) {
    const float* x    = (const float*)d_in[0];   // [16,256,56,56]
    const float* U    = (const float*)d_in[1];   // [256,64]
    const float* S    = (const float*)d_in[2];   // [64,64]
    const float* V    = (const float*)d_in[3];   // [2304,64]
    const float* bias = (const float*)d_in[4];   // [256]
    float* out = (float*)d_out;                  // [16,256,56,56] fp32

    char* ws = (char*)d_ws;
    u16* xb = (u16*)ws;                                   // 16*58*58*256*2 = 27,557,888 B
    u16* Vt = (u16*)(ws + 27557888);                      //   294,912 B
    u16* W2 = (u16*)(ws + 27557888 + 294912);             //    32,768 B
    u16* y1 = (u16*)(ws + 27557888 + 294912 + 32768);     // 6,422,528 B  (total ~34.3 MB)

    k_us   <<<64,  256, 0, stream>>>(U, S, W2);
    k_vperm<<<576, 256, 0, stream>>>(V, Vt);
    k_pad  <<<928, 256, 0, stream>>>(x, xb);
    k_convA<<<896, 256, 0, stream>>>(xb, Vt, y1);
    k_gemmB<<<784, 256, 0, stream>>>(y1, W2, bias, out);
}

// Round 2
// 172.829 us; speedup vs baseline: 1.2986x; 1.2986x over previous
//
#include <hip/hip_runtime.h>
#include <stdint.h>

typedef unsigned short u16;
typedef __attribute__((ext_vector_type(8))) short short8;   // 8 x bf16 (4 VGPRs)
typedef __attribute__((ext_vector_type(4))) float f32x4;    // 4 x fp32 acc

__device__ __forceinline__ u16 f2bf(float f) {
    union { float f; uint32_t u; } v; v.f = f;
    return (u16)((v.u + (0x7FFFu + ((v.u >> 16) & 1u))) >> 16);   // RNE
}

// ---------------- P1: W2[o][j] = sum_i U[o][i] * S[i][j]  (256x64, bf16 out) ----
__global__ void k_us(const float* __restrict__ U, const float* __restrict__ S,
                     u16* __restrict__ W2) {
    int t = blockIdx.x * 256 + threadIdx.x;        // 16384 threads
    int o = t >> 6, j = t & 63;
    float acc = 0.f;
#pragma unroll 8
    for (int i = 0; i < 64; ++i) acc += U[o * 64 + i] * S[i * 64 + j];
    W2[t] = f2bf(acc);
}

// ---------------- P2: Vt[r][tap*256 + c] = V[c*9 + tap][r]  (bf16) --------------
__global__ void k_vperm(const float* __restrict__ V, u16* __restrict__ Vt) {
    int t = blockIdx.x * 256 + threadIdx.x;        // 147456 threads
    int c = t & 255;
    int tap = (t >> 8) % 9;
    int r = t / 2304;
    Vt[t] = f2bf(V[(c * 9 + tap) * 64 + r]);
}

// ---------------- P3: coalesced LDS-tiled transpose+pad  -----------------------
// xb[b][hp][wp][c] (bf16, [16][58][58][256]) from x[b][c][h][w] fp32.
// block = (b, hp, cgroup of 128 c). Reads coalesced along w; LDS holds
// u32-packed channel pairs [cpair][w] (stride 57 -> bank walk 25, 2-way free);
// writes coalesced along c (64 lanes x 4B = 256 B contiguous).
__global__ __launch_bounds__(256) void k_tr(const float* __restrict__ x,
                                            u16* __restrict__ xb) {
    __shared__ uint32_t lds[64 * 57];               // 14592 B
    int bi = blockIdx.x;                            // 16*58*2 = 1856
    int cg = bi & 1;
    int hp = (bi >> 1) % 58;
    int b  = bi / 116;
    int c0 = cg * 128;
    int tid = threadIdx.x;

    uint32_t* xbrow32 = (uint32_t*)(xb + ((size_t)(b * 58 + hp) * 58) * 256 + c0);
    // row wp has u32 base offset wp*128 (256 u16 per row / 2)

    if (hp == 0 || hp == 57) {                      // border row: all zeros
        for (int i = tid; i < 58 * 64; i += 256)
            xbrow32[(i >> 6) * 128 + (i & 63)] = 0u;
        return;
    }

    int h = hp - 1;
    int w = tid & 63;                               // 56 valid
    int cpq = tid >> 6;                             // 0..3
    const float* xbase = x + ((size_t)(b * 256 + c0) * 3136) + h * 56 + w;
    if (w < 56) {
#pragma unroll
        for (int k = 0; k < 16; ++k) {
            int cp = cpq * 16 + k;                  // channel pair 0..63
            float a0 = xbase[(size_t)(2 * cp) * 3136];
            float a1 = xbase[(size_t)(2 * cp + 1) * 3136];
            lds[cp * 57 + w] = (uint32_t)f2bf(a0) | ((uint32_t)f2bf(a1) << 16);
        }
    }
    __syncthreads();

    int cpair = tid & 63;
    int wpq = tid >> 6;
#pragma unroll
    for (int wp = wpq; wp < 58; wp += 4) {
        uint32_t v = (wp == 0 || wp == 57) ? 0u : lds[cpair * 57 + (wp - 1)];
        xbrow32[wp * 128 + cpair] = v;
    }
}

// ---------------- Stage A: y1[b][l][r] = conv(xb, Vt)  -------------------------
// block = one (b, h) output row: BM=64 (r), BN=64 (w; 56 valid), K=2304
// LDS tile: [di 0..2][wp 0..65][c-slot 40 (32 used)] bf16, all 9 taps reuse it.
#define WPS 40                                      // padded c-stride (bank spread)
__global__ __launch_bounds__(256) void k_convA(const u16* __restrict__ xb,
                                               const u16* __restrict__ Vt,
                                               u16* __restrict__ y1) {
    __shared__ u16 lds_x[3 * 66 * WPS];             // 15840 B
    int bi = blockIdx.x;                            // 896 = 16*56
    int b = bi & 15, h = bi >> 4;
    int tid = threadIdx.x;
    int wv = tid >> 6;                              // wave id: m-tile (16 r's)
    int ln = tid & 63;
    int lane15 = ln & 15, quad = ln >> 4;

    f32x4 acc[4];
#pragma unroll
    for (int nt = 0; nt < 4; ++nt) acc[nt] = (f32x4){0.f, 0.f, 0.f, 0.f};

    for (int chunk = 0; chunk < 8; ++chunk) {
        int c0 = chunk * 32;
        // hoist all 9 A-fragments: L2-latency loads overlap barrier + staging
        short8 a[9];
#pragma unroll
        for (int tap = 0; tap < 9; ++tap)
            a[tap] = *(const short8*)(Vt + (size_t)(wv * 16 + lane15) * 2304
                                      + tap * 256 + c0 + quad * 8);
        __syncthreads();
        // stage 3 rows x 66 wp x 32 c as 16B chunks: 3*66*4 = 792 chunks
        for (int idx = tid; idx < 792; idx += 256) {
            int q  = idx & 3;
            int rm = idx >> 2;
            int wp = rm % 66;
            int di = rm / 66;
            uint4 val = make_uint4(0u, 0u, 0u, 0u);
            if (wp < 58) {
                const uint4* src = (const uint4*)(xb +
                    (((size_t)(b * 58 + (h + di)) * 58 + wp) << 8) + c0 + q * 8);
                val = *src;
            }
            *(uint4*)&lds_x[(di * 66 + wp) * WPS + q * 8] = val;
        }
        __syncthreads();
#pragma unroll
        for (int tap = 0; tap < 9; ++tap) {
            const int di = tap / 3, dj = tap % 3;
#pragma unroll
            for (int nt = 0; nt < 4; ++nt) {
                int n = nt * 16 + lane15;
                short8 bv = *(const short8*)&lds_x[(di * 66 + n + dj) * WPS + quad * 8];
                acc[nt] = __builtin_amdgcn_mfma_f32_16x16x32_bf16(a[tap], bv, acc[nt], 0, 0, 0);
            }
        }
    }
    // epilogue: C layout col=lane&15 (n), row=quad*4+reg (m) -> y1[b][l][r] bf16
#pragma unroll
    for (int nt = 0; nt < 4; ++nt) {
        int n = nt * 16 + lane15;
        if (n < 56) {
            int l = h * 56 + n;
            int r = wv * 16 + quad * 4;
            uint2 pv;
            pv.x = (uint32_t)f2bf(acc[nt][0]) | ((uint32_t)f2bf(acc[nt][1]) << 16);
            pv.y = (uint32_t)f2bf(acc[nt][2]) | ((uint32_t)f2bf(acc[nt][3]) << 16);
            *(uint2*)(y1 + ((size_t)(b * 3136 + l) << 6) + r) = pv;
        }
    }
}

// ---------------- Stage B: out[b][o][l] = W2[o][:] . y1[b][l][:] + bias[o] -----
// block: BM=256 (wave wv -> o in [wv*64, wv*64+64)), BN=64 (l), K=64
__global__ __launch_bounds__(256) void k_gemmB(const u16* __restrict__ y1,
                                               const u16* __restrict__ W2,
                                               const float* __restrict__ bias,
                                               float* __restrict__ out) {
    __shared__ u16 lds_y[64 * 72];                  // 9216 B, 72 stride = bank spread
    int bi = blockIdx.x;                            // 784 = 16*49
    int b = bi % 16, lt = bi / 16;
    int l0 = lt * 64;
    int tid = threadIdx.x;
    int wv = tid >> 6, ln = tid & 63;
    int lane15 = ln & 15, quad = ln >> 4;

    // stage y1 tile [64 n][64 r]: 64*8 = 512 16B chunks
    for (int idx = tid; idx < 512; idx += 256) {
        int q = idx & 7, n = idx >> 3;
        uint4 v = *(const uint4*)(y1 + (((size_t)(b * 3136 + l0 + n)) << 6) + q * 8);
        *(uint4*)&lds_y[n * 72 + q * 8] = v;
    }
    __syncthreads();

    f32x4 acc[4][4];
#pragma unroll
    for (int mt = 0; mt < 4; ++mt)
#pragma unroll
        for (int nt = 0; nt < 4; ++nt) acc[mt][nt] = (f32x4){0.f, 0.f, 0.f, 0.f};

    int o0 = wv * 64;
#pragma unroll
    for (int ks = 0; ks < 64; ks += 32) {
        short8 a[4];
#pragma unroll
        for (int mt = 0; mt < 4; ++mt)
            a[mt] = *(const short8*)(W2 + (size_t)(o0 + mt * 16 + lane15) * 64
                                     + ks + quad * 8);
#pragma unroll
        for (int nt = 0; nt < 4; ++nt) {
            short8 bv = *(const short8*)&lds_y[(nt * 16 + lane15) * 72 + ks + quad * 8];
#pragma unroll
            for (int mt = 0; mt < 4; ++mt)
                acc[mt][nt] = __builtin_amdgcn_mfma_f32_16x16x32_bf16(a[mt], bv, acc[mt][nt], 0, 0, 0);
        }
    }

#pragma unroll
    for (int mt = 0; mt < 4; ++mt) {
        int ob = o0 + mt * 16 + quad * 4;
#pragma unroll
        for (int reg = 0; reg < 4; ++reg) {
            int o = ob + reg;
            float bvl = bias[o];
            float* orow = out + ((size_t)(b * 256 + o)) * 3136 + l0 + lane15;
#pragma unroll
            for (int nt = 0; nt < 4; ++nt)
                orow[nt * 16] = acc[mt][nt][reg] + bvl;
        }
    }
}

extern "C" void kernel_launch(void* const* d_in, const int* in_sizes, int n_in,
                              void* d_out, int out_size, void* d_ws, size_t ws_size,
                              hipStream_t stream) {
    const float* x    = (const float*)d_in[0];   // [16,256,56,56]
    const float* U    = (const float*)d_in[1];   // [256,64]
    const float* S    = (const float*)d_in[2];   // [64,64]
    const float* V    = (const float*)d_in[3];   // [2304,64]
    const float* bias = (const float*)d_in[4];   // [256]
    float* out = (float*)d_out;                  // [16,256,56,56] fp32

    char* ws = (char*)d_ws;
    u16* xb = (u16*)ws;                                   // 16*58*58*256*2 = 27,557,888 B
    u16* Vt = (u16*)(ws + 27557888);                      //   294,912 B
    u16* W2 = (u16*)(ws + 27557888 + 294912);             //    32,768 B
    u16* y1 = (u16*)(ws + 27557888 + 294912 + 32768);     // 6,422,528 B  (total ~34.3 MB)

    k_us   <<<64,   256, 0, stream>>>(U, S, W2);
    k_vperm<<<576,  256, 0, stream>>>(V, Vt);
    k_tr   <<<1856, 256, 0, stream>>>(x, xb);
    k_convA<<<896,  256, 0, stream>>>(xb, Vt, y1);
    k_gemmB<<<784,  256, 0, stream>>>(y1, W2, bias, out);
}